// Round 16
// baseline (293.989 us; speedup 1.0000x reference)
//
#include <hip/hip_runtime.h>
#include <cstdint>
#include <cstddef>

// ---------------------------------------------------------------------------
// BatchTreeEncoder on MFMA: A=4, D=7, B=64, E=128, H=128, N_NODES=5461
// Leaves: H_leaf[v][128] precomputed once (bf16, bitwise-identical).
// Levels 5..0: fused attn+gru, half-node blocks (32 batch rows), grid 2n.
// Max strategy: child-max from staged tile at all levels; own-h at root only.
// Register state ~88 unified (56 VGPR + 32 AGPR) = 2 blocks/CU at (512,4).
// DO NOT tighten launch bounds or add loop-carried state: budgets <=85
// (3 blk/CU) spill to scratch — verified rounds 7/10/11/14.
// THIS ROUND: child-tile staging via __builtin_amdgcn_global_load_lds
// (linear LDS dest + inverse-swizzled per-lane source; readers unchanged).
// Removes the VGPR round-trip + ds_writes from the staging path (VALU diet).
// ---------------------------------------------------------------------------

typedef short  bf16x8 __attribute__((ext_vector_type(8)));
typedef float  f32x4  __attribute__((ext_vector_type(4)));
typedef const __attribute__((address_space(1))) unsigned int* gptr_t;
typedef __attribute__((address_space(3))) unsigned int* lptr_t;

// workspace layout (bytes), total ~50 MB
#define WS_ACC    0u                         // 32*8192*4 = 1 MB
#define WS_WIH    1048576u                   // 384*128*2 = 96 KB
#define WS_WHH    (WS_WIH + 98304u)
#define WS_SWT    (WS_WHH + 98304u)          // 128*128*2 = 32 KB
#define WS_EMBB   (WS_SWT + 32768u)          // 50000*128*2 = 12.8 MB
#define WS_HLEAF  (WS_EMBB + 12800000u)      // 50000*128*2 = 12.8 MB
#define WS_HA     (WS_HLEAF + 12800000u)     // even levels out, max d=4: 4 MB
#define WS_HB     (WS_HA + 4194304u)         // odd levels out, max d=5: 16 MB

__device__ __forceinline__ float sigm(float x)   { return 1.0f / (1.0f + __expf(-x)); }
__device__ __forceinline__ float tanhf_(float x) { return 1.0f - 2.0f / (1.0f + __expf(2.0f * x)); }

__device__ __forceinline__ unsigned short f2b(float f) {
  unsigned u = __float_as_uint(f);
  u += 0x7fffu + ((u >> 16) & 1u);     // RNE (no NaN here)
  return (unsigned short)(u >> 16);
}
__device__ __forceinline__ float b2f(unsigned short s) {
  return __uint_as_float(((unsigned)s) << 16);
}

__device__ __forceinline__ unsigned fenc(float f) {
  unsigned u = __float_as_uint(f);
  return (u & 0x80000000u) ? ~u : (u | 0x80000000u);
}
__device__ __forceinline__ float fdec(unsigned e) {
  unsigned u = (e & 0x80000000u) ? (e & 0x7fffffffu) : ~e;
  return __uint_as_float(u);
}

__device__ __forceinline__ f32x4 mfma16(bf16x8 a, bf16x8 b, f32x4 c) {
  return __builtin_amdgcn_mfma_f32_16x16x32_bf16(a, b, c, 0, 0, 0);
}

__global__ __launch_bounds__(256) void decode_out(const unsigned* __restrict__ acc,
                                                  float* __restrict__ out) {
  int i = blockIdx.x * 256 + threadIdx.x;              // grid 32
  unsigned m = 0u;
  for (int s = 0; s < 32; ++s) m = max(m, acc[s * 8192 + i]);
  out[i] = fdec(m);
}

// one-shot prep: emb->bf16, weights->bf16, sent_w transpose, acc init
__global__ __launch_bounds__(256) void prep_all(const float* __restrict__ emb,
                                                const float* __restrict__ wih,
                                                const float* __restrict__ whh,
                                                const float* __restrict__ sw,
                                                unsigned short* __restrict__ embb,
                                                unsigned short* __restrict__ wihb,
                                                unsigned short* __restrict__ whhb,
                                                unsigned short* __restrict__ swtb,
                                                unsigned* __restrict__ acc) {
  size_t idx = (size_t)blockIdx.x * 256 + threadIdx.x;   // grid 7722
  if (idx < 1600000u) {                                  // 6.4M floats as float4
    float4 v = *(const float4*)(emb + idx * 4);
    ushort4 o; o.x = f2b(v.x); o.y = f2b(v.y); o.z = f2b(v.z); o.w = f2b(v.w);
    *(ushort4*)(embb + idx * 4) = o;
  } else if (idx < 1714688u) {                           // 114688 weight elems
    int i = (int)(idx - 1600000u);
    if (i < 49152)       wihb[i] = f2b(wih[i]);
    else if (i < 98304)  whhb[i - 49152] = f2b(whh[i - 49152]);
    else { int j = i - 98304; int k = j >> 7, h = j & 127; swtb[j] = f2b(sw[h * 128 + k]); }
  } else {                                               // 262144 acc words
    acc[idx - 1714688u] = 0u;
  }
}

// ---------------------------------------------------------------------------
// prep_hleaf: H_leaf[v][:] = leaf GRU output for token v (bitwise-identical
// to the old leaf path). grid 782 x 512. Staging via global_load_lds.
// ---------------------------------------------------------------------------
__global__ __launch_bounds__(512, 2) void prep_hleaf(
    const unsigned short* __restrict__ embb,
    const unsigned short* __restrict__ wih,
    const float*          __restrict__ b_ih,
    const float*          __restrict__ b_hh,
    unsigned short*       __restrict__ H)
{
  __shared__ unsigned short lds[64 * 128];
  __shared__ unsigned short hvb[64 * 128];
  const int t = threadIdx.x;
  const int base = blockIdx.x * 64;

  const int w = __builtin_amdgcn_readfirstlane(t >> 6);
  const int lane = t & 63, l = lane & 15, q = lane >> 4;
  const int j = w * 16 + l;

  // stage 64 sequential embb rows direct-to-LDS (swizzle via source chunk)
#pragma unroll
  for (int i = 0; i < 2; ++i) {
    int m = w * 4 + 32 * i + (lane >> 4);
    int c = (lane & 15) ^ (m & 15);
    int v = base + m; if (v > 49999) v = 49999;
    __builtin_amdgcn_global_load_lds(
        (gptr_t)(embb + (size_t)v * 128 + c * 8),
        (lptr_t)(lds + (w * 4 + 32 * i) * 128), 16, 0, 0);
  }

  bf16x8 Br[4], Bz[4], Bn[4];
#pragma unroll
  for (int ks = 0; ks < 4; ++ks) {
    const int ko = ks * 32 + q * 8;
    Br[ks] = *(const bf16x8*)(wih + (size_t)j * 128 + ko);
    Bz[ks] = *(const bf16x8*)(wih + (size_t)(128 + j) * 128 + ko);
    Bn[ks] = *(const bf16x8*)(wih + (size_t)(256 + j) * 128 + ko);
  }
  const float bR = b_ih[j] + b_hh[j];
  const float bZ = b_ih[128 + j] + b_hh[128 + j];
  const float bN = b_ih[256 + j];
  const float bH = b_hh[256 + j];

  f32x4 Cr[4] = {{0,0,0,0},{0,0,0,0},{0,0,0,0},{0,0,0,0}};
  f32x4 Cz[4] = {{0,0,0,0},{0,0,0,0},{0,0,0,0},{0,0,0,0}};
  f32x4 Cn[4] = {{0,0,0,0},{0,0,0,0},{0,0,0,0},{0,0,0,0}};
  __syncthreads();

#pragma unroll
  for (int ks = 0; ks < 4; ++ks) {
    bf16x8 A[4];
#pragma unroll
    for (int mt = 0; mt < 4; ++mt) {
      int m = mt * 16 + l, c = ks * 4 + q;
      A[mt] = *(const bf16x8*)(lds + m * 128 + (((c ^ l) & 15) << 3));
    }
#pragma unroll
    for (int mt = 0; mt < 4; ++mt) {
      Cr[mt] = mfma16(A[mt], Br[ks], Cr[mt]);
      Cz[mt] = mfma16(A[mt], Bz[ks], Cz[mt]);
      Cn[mt] = mfma16(A[mt], Bn[ks], Cn[mt]);
    }
  }

#pragma unroll
  for (int mt = 0; mt < 4; ++mt)
#pragma unroll
    for (int e = 0; e < 4; ++e) {
      int b = mt * 16 + q * 4 + e;              // C/D: col=lane&15, row=quad*4+reg
      float r  = sigm(Cr[mt][e] + bR);
      float z  = sigm(Cz[mt][e] + bZ);
      float nv = tanhf_(Cn[mt][e] + bN + r * bH);
      float hv = (1.0f - z) * nv;
      hvb[b * 128 + (j ^ (q << 4))] = f2b(hv);
    }
  __syncthreads();

#pragma unroll
  for (int i = 0; i < 2; ++i) {
    int g = t + 512 * i;
    int b = g >> 4, c8 = (g & 15) * 8;
    int qq = (b >> 2) & 3;
    if (base + b < 50000) {
      uint4 v = *(const uint4*)(hvb + b * 128 + (c8 ^ (qq << 4)));
      *(uint4*)(H + (size_t)(base + b) * 128 + c8) = v;
    }
  }
}

// ---------------------------------------------------------------------------
// FUSED attn+gru, half-node blocks: grid 2n, block 512 (8 waves).
// Block (p, half) handles batch rows half*32..+32 of parent p.
// 4 barriers: (1) chs staged, (2) spart accumulated, (3) atile ready,
// (4) hvb ready. Child tile staged via global_load_lds: linear LDS dest +
// inverse-swizzled per-lane source (readers keep the same swizzle formula).
// CHILD-MAX from chs at all levels; own-h max at the ROOT block only.
// ---------------------------------------------------------------------------
template <bool LEAF, bool ROOT>
__global__ __launch_bounds__(512, 4) void attn_gru(
    const unsigned short* __restrict__ hch,   // child h (non-leaf), rows p*256..
    const int*            __restrict__ tokc,  // LEAF: children tokens
    const unsigned short* __restrict__ hleaf, // LEAF: per-vocab leaf h
    const unsigned short* __restrict__ swt,   // 128x128 bf16 [k_u][h]
    const float*          __restrict__ sb,
    const float*          __restrict__ ctx,
    const int*            __restrict__ tok,   // THIS level's tokens
    const unsigned short* __restrict__ embb,
    const unsigned short* __restrict__ wih,
    const unsigned short* __restrict__ whh,
    const float*          __restrict__ b_ih,
    const float*          __restrict__ b_hh,
    unsigned short*       __restrict__ hout,
    unsigned*             __restrict__ acc)
{
  __shared__ unsigned short chs[128 * 128];   // 32 KB child tile
  __shared__ unsigned short atile[32 * 256];  // 16 KB gru A tile (x || h0)
  __shared__ unsigned short hvb[32 * 128];    // 8 KB hv staging
  __shared__ float spart[128];                // s partial sums (atomicAdd)

  const int p2 = blockIdx.x;
  const int p = p2 >> 1, half = p2 & 1;
  const int t = threadIdx.x;
  const int sm = t >> 4, sc = t & 15;

  const int w = __builtin_amdgcn_readfirstlane(t >> 6);
  const int wm = w >> 2, wn = w & 3;          // wm: row-half (64), wn: col-32
  const int lane = t & 63, l = lane & 15, q = lane >> 4;
  const int j = w * 16 + l;

  // init spart before barrier 1 (accumulated after it)
  if (t < 128) spart[t] = 0.0f;

  // x gather for this half-node -> atile x-region (disjoint from chs; read
  // only after barrier 3). Row stride 512B breaks lane-contiguity -> stays
  // as load + ds_write.
  {
    const int* tp = tok + p * 64 + half * 32;
    uint4 px = *(const uint4*)(embb + (size_t)tp[sm] * 128 + sc * 8);
    *(uint4*)(atile + sm * 256 + ((sc ^ (sm & 15)) << 3)) = px;
  }

  // stage 128 child rows direct-to-LDS: each wave covers 1 KB linear LDS
  // (lane*16B); source chunk inverse-swizzled c = (lane&15)^(m&15).
  {
    const int* tokp = LEAF ? (tokc + p * 256) : (const int*)nullptr;
#pragma unroll
    for (int i = 0; i < 4; ++i) {
      int m  = w * 4 + 32 * i + (lane >> 4);
      int c  = (lane & 15) ^ (m & 15);
      int bg = (m >> 5) * 64 + half * 32 + (m & 31);
      const unsigned short* src;
      if constexpr (LEAF) src = hleaf + (size_t)tokp[bg] * 128 + c * 8;
      else                src = hch + ((size_t)p * 256 + bg) * 128 + c * 8;
      __builtin_amdgcn_global_load_lds(
          (gptr_t)src, (lptr_t)(chs + (w * 4 + 32 * i) * 128), 16, 0, 0);
    }
  }

  bf16x8 Bs[2][4];
#pragma unroll
  for (int nt = 0; nt < 2; ++nt)
#pragma unroll
    for (int ks = 0; ks < 4; ++ks)
      Bs[nt][ks] = *(const bf16x8*)(swt + (size_t)(wn * 32 + nt * 16 + l) * 128 + ks * 32 + q * 8);

  f32x4 Cu[4][2] = {};
  __syncthreads();                                      // (1) chs staged

  // attn MFMA: wave covers rows wm*64..+64, cols wn*32..+32
#pragma unroll
  for (int ks = 0; ks < 4; ++ks) {
#pragma unroll
    for (int mt = 0; mt < 4; ++mt) {
      int m = wm * 64 + mt * 16 + l;
      int c = ks * 4 + q;
      bf16x8 A = *(const bf16x8*)(chs + m * 128 + (((c ^ (m & 15)) & 15) << 3));
      Cu[mt][0] = mfma16(A, Bs[0][ks], Cu[mt][0]);
      Cu[mt][1] = mfma16(A, Bs[1][ks], Cu[mt][1]);
    }
  }

  const float sb0 = sb[wn * 32 + l],  sb1 = sb[wn * 32 + 16 + l];
  const float cx0 = ctx[wn * 32 + l], cx1 = ctx[wn * 32 + 16 + l];
#pragma unroll
  for (int mt = 0; mt < 4; ++mt) {
    float pe[4];
#pragma unroll
    for (int e = 0; e < 4; ++e)
      pe[e] = tanhf_(Cu[mt][0][e] + sb0) * cx0 + tanhf_(Cu[mt][1][e] + sb1) * cx1;
#pragma unroll
    for (int mask = 1; mask < 16; mask <<= 1)
#pragma unroll
      for (int e = 0; e < 4; ++e)
        pe[e] += __shfl_xor(pe[e], mask, 16);
    if (l == 0) {
      int r = wm * 64 + mt * 16 + q * 4;
#pragma unroll
      for (int e = 0; e < 4; ++e) atomicAdd(&spart[r + e], pe[e]);
    }
  }
  __syncthreads();                                      // (2) spart accumulated

  // per-thread softmax (redundant across the 16 threads sharing rb)
  float al[4];
  {
    int rb = t >> 4;
    float sv[4];
#pragma unroll
    for (int a = 0; a < 4; ++a) sv[a] = tanhf_(spart[a * 32 + rb]);
    float m = fmaxf(fmaxf(sv[0], sv[1]), fmaxf(sv[2], sv[3]));
    float e0 = __expf(sv[0] - m), e1 = __expf(sv[1] - m);
    float e2 = __expf(sv[2] - m), e3 = __expf(sv[3] - m);
    float inv = 1.0f / (e0 + e1 + e2 + e3);
    al[0] = e0 * inv; al[1] = e1 * inv; al[2] = e2 * inv; al[3] = e3 * inv;
  }

  // alpha-weighted sum -> registers (thread t: row rb=t>>4, chunk c=t&15)
  float o[8] = {0, 0, 0, 0, 0, 0, 0, 0};
  {
    int rb = t >> 4, c = t & 15;
#pragma unroll
    for (int a = 0; a < 4; ++a) {
      int m = a * 32 + rb;
      const unsigned short* rp = chs + m * 128 + ((c ^ (m & 15)) << 3);
#pragma unroll
      for (int k = 0; k < 8; ++k) o[k] += al[a] * b2f(rp[k]);
    }
  }

  // CHILD-MAX (level d+1's h) from chs — ALL levels.
  // Lane-contiguous acc mapping: word = half*4096 + t + 512e == (bg*128+j).
  float mxv[8];
  {
    const int jj = t & 127, cc = jj >> 3;
#pragma unroll
    for (int e = 0; e < 8; ++e) mxv[e] = -1e30f;
#pragma unroll
    for (int a = 0; a < 4; ++a)
#pragma unroll
      for (int e = 0; e < 8; ++e) {
        int rb = (t >> 7) + 4 * e, m = a * 32 + rb;
        float v = b2f(chs[m * 128 + (((cc ^ (m & 15)) & 15) << 3) + (jj & 7)]);
        mxv[e] = fmaxf(mxv[e], v);
      }
  }

  // h0 -> atile h0-region (x-region already written at block start)
  {
    int rb = t >> 4, c = t & 15;
    ushort4 ha, hb;
    ha.x = f2b(o[0]); ha.y = f2b(o[1]); ha.z = f2b(o[2]); ha.w = f2b(o[3]);
    hb.x = f2b(o[4]); hb.y = f2b(o[5]); hb.z = f2b(o[6]); hb.w = f2b(o[7]);
    unsigned short* dst = atile + rb * 256 + ((16 | ((c ^ (rb & 15)) & 15)) << 3);
    *(ushort4*)dst = ha;
    *(ushort4*)(dst + 4) = hb;
  }

  const unsigned short* wI = wih + (size_t)j * 128 + q * 8;
  const unsigned short* wH = whh + (size_t)j * 128 + q * 8;
  const float bR = b_ih[j] + b_hh[j];
  const float bZ = b_ih[128 + j] + b_hh[128 + j];
  const float bN = b_ih[256 + j];
  const float bH = b_hh[256 + j];
  __syncthreads();                                      // (3) atile ready

  // gru MFMA, B triple loop-loaded with 1-deep prefetch
  f32x4 Cr[2] = {{0,0,0,0},{0,0,0,0}};
  f32x4 Cz[2] = {{0,0,0,0},{0,0,0,0}};
  f32x4 Cn[2] = {{0,0,0,0},{0,0,0,0}};
  f32x4 Ch[2] = {{0,0,0,0},{0,0,0,0}};

  bf16x8 b0 = *(const bf16x8*)(wI);
  bf16x8 b1 = *(const bf16x8*)(wI + 128 * 128);
  bf16x8 b2 = *(const bf16x8*)(wI + 256 * 128);

#pragma unroll
  for (int ks = 0; ks < 8; ++ks) {
    bf16x8 c0 = b0, c1 = b1, c2 = b2;
    if (ks + 1 < 8) {
      const unsigned short* base = (ks + 1 >= 4) ? wH : wI;
      const int ko = ((ks + 1) & 3) * 32;
      b0 = *(const bf16x8*)(base + ko);
      b1 = *(const bf16x8*)(base + 128 * 128 + ko);
      b2 = *(const bf16x8*)(base + 256 * 128 + ko);
    }
#pragma unroll
    for (int mt = 0; mt < 2; ++mt) {
      int m = mt * 16 + l;
      int c = ks * 4 + q;
      bf16x8 Amt = *(const bf16x8*)(atile + m * 256 + (((c & 16) | ((c ^ l) & 15)) << 3));
      Cr[mt] = mfma16(Amt, c0, Cr[mt]);
      Cz[mt] = mfma16(Amt, c1, Cz[mt]);
      if (ks < 4) Cn[mt] = mfma16(Amt, c2, Cn[mt]);
      else        Ch[mt] = mfma16(Amt, c2, Ch[mt]);
    }
  }

  // gates; hv -> hvb (q-swizzled); ROOT tracks own-h max in regs
  float mx[2][4];
#pragma unroll
  for (int mt = 0; mt < 2; ++mt) {
#pragma unroll
    for (int e = 0; e < 4; ++e) {
      const int b = mt * 16 + q * 4 + e;        // C/D: col=lane&15, row=quad*4+reg
      float r  = sigm(Cr[mt][e] + bR);
      float z  = sigm(Cz[mt][e] + bZ);
      float nv = tanhf_(Cn[mt][e] + bN + r * (Ch[mt][e] + bH));
      int c16 = j >> 3;
      float hp = b2f(atile[b * 256 + ((16 | ((c16 ^ (b & 15)) & 15)) << 3) + (j & 7)]);
      float hv = (1.0f - z) * nv + z * hp;
      hvb[b * 128 + (j ^ (q << 4))] = f2b(hv);
      if constexpr (ROOT) mx[mt][e] = hv;
    }
  }
  __syncthreads();                                      // (4) hvb ready

  // coalesced hout store (1 chunk/thread)
  {
    int qq = (sm >> 2) & 3;
    uint4 v = *(const uint4*)(hvb + sm * 128 + ((sc * 8) ^ (qq << 4)));
    *(uint4*)(hout + ((size_t)p * 64 + half * 32 + sm) * 128 + sc * 8) = v;
  }

  // atomics at TRUE kernel end (no barrier after)
  unsigned* accs = acc + (p2 & 31) * 8192;
#pragma unroll
  for (int e = 0; e < 8; ++e)
    atomicMax(accs + half * 4096 + t + 512 * e, fenc(mxv[e]));
  if constexpr (ROOT) {
#pragma unroll
    for (int mt = 0; mt < 2; ++mt)
#pragma unroll
      for (int e = 0; e < 4; ++e) {
        const int bg = half * 32 + mt * 16 + q * 4 + e;
        atomicMax(accs + bg * 128 + j, fenc(mx[mt][e]));
      }
  }
}

extern "C" void kernel_launch(void* const* d_in, const int* in_sizes, int n_in,
                              void* d_out, int out_size, void* d_ws, size_t ws_size,
                              hipStream_t stream) {
  const int*   tokens = (const int*)d_in[0];
  const float* emb    = (const float*)d_in[1];
  const float* sent_w = (const float*)d_in[2];
  const float* sent_b = (const float*)d_in[3];
  const float* ctx_w  = (const float*)d_in[4];
  const float* w_ih   = (const float*)d_in[5];
  const float* w_hh   = (const float*)d_in[6];
  const float* b_ih   = (const float*)d_in[7];
  const float* b_hh   = (const float*)d_in[8];

  char* ws = (char*)d_ws;
  unsigned*       acc  = (unsigned*)(ws + WS_ACC);
  unsigned short* wihb = (unsigned short*)(ws + WS_WIH);
  unsigned short* whhb = (unsigned short*)(ws + WS_WHH);
  unsigned short* swtb = (unsigned short*)(ws + WS_SWT);
  unsigned short* embb = (unsigned short*)(ws + WS_EMBB);
  unsigned short* hlf  = (unsigned short*)(ws + WS_HLEAF);
  unsigned short* hA   = (unsigned short*)(ws + WS_HA);
  unsigned short* hB   = (unsigned short*)(ws + WS_HB);

  hipLaunchKernelGGL(prep_all, dim3(7722), dim3(256), 0, stream,
                     emb, w_ih, w_hh, sent_w, embb, wihb, whhb, swtb, acc);
  hipLaunchKernelGGL(prep_hleaf, dim3(782), dim3(512), 0, stream,
                     embb, wihb, b_ih, b_hh, hlf);

  static const int offs[7] = {0, 1, 5, 21, 85, 341, 1365};
  const int* tok6 = tokens + (size_t)1365 * 64;

  for (int d = 5; d >= 0; --d) {
    int n = 1 << (2 * d);
    unsigned short* hout  = (d & 1) ? hB : hA;
    unsigned short* child = (d & 1) ? hA : hB;   // level d+1 output (non-leaf)
    if (d == 5) {
      hipLaunchKernelGGL((attn_gru<true, false>), dim3(2 * n), dim3(512), 0, stream,
                         (const unsigned short*)nullptr, tok6, hlf,
                         swtb, sent_b, ctx_w,
                         tokens + (size_t)offs[5] * 64, embb, wihb, whhb,
                         b_ih, b_hh, hout, acc);
    } else if (d > 0) {
      hipLaunchKernelGGL((attn_gru<false, false>), dim3(2 * n), dim3(512), 0, stream,
                         child, (const int*)nullptr, (const unsigned short*)nullptr,
                         swtb, sent_b, ctx_w,
                         tokens + (size_t)offs[d] * 64, embb, wihb, whhb,
                         b_ih, b_hh, hout, acc);
    } else {
      hipLaunchKernelGGL((attn_gru<false, true>), dim3(2 * n), dim3(512), 0, stream,
                         child, (const int*)nullptr, (const unsigned short*)nullptr,
                         swtb, sent_b, ctx_w,
                         tokens + (size_t)offs[0] * 64, embb, wihb, whhb,
                         b_ih, b_hh, hout, acc);
    }
  }
  hipLaunchKernelGGL(decode_out, dim3(32), dim3(256), 0, stream, acc, (float*)d_out);
}

// Round 17
// 289.412 us; speedup vs baseline: 1.0158x; 1.0158x over previous
//
#include <hip/hip_runtime.h>
#include <cstdint>
#include <cstddef>

// ---------------------------------------------------------------------------
// BatchTreeEncoder on MFMA: A=4, D=7, B=64, E=128, H=128, N_NODES=5461
// Leaves: H_leaf[v][128] precomputed once (bf16, bitwise-identical).
// Levels 5..0: fused attn+gru, half-node blocks (32 batch rows), grid 2n.
// Max strategy: child-max from staged tile at all levels; own-h at root only.
// Register state ~88 unified (56 VGPR + 32 AGPR) = 2 blocks/CU at (512,4).
// Walls (do not re-attempt): budgets <=85 (3 blk/CU) spill (r7/10/11/14);
// persistence spills (r10/11); global_load_lds staging is -4%/level (r16).
// THIS ROUND: emb fp32->bf16 conversion merged INTO prep_hleaf (reads fp32
// emb once, feeds LDS + writes embb); prep_all shrinks to weights+acc.
// Deletes one full 25.6 MB pass over the embedding table.
// ---------------------------------------------------------------------------

typedef short  bf16x8 __attribute__((ext_vector_type(8)));
typedef float  f32x4  __attribute__((ext_vector_type(4)));

// workspace layout (bytes), total ~50 MB
#define WS_ACC    0u                         // 32*8192*4 = 1 MB
#define WS_WIH    1048576u                   // 384*128*2 = 96 KB
#define WS_WHH    (WS_WIH + 98304u)
#define WS_SWT    (WS_WHH + 98304u)          // 128*128*2 = 32 KB
#define WS_EMBB   (WS_SWT + 32768u)          // 50000*128*2 = 12.8 MB
#define WS_HLEAF  (WS_EMBB + 12800000u)      // 50000*128*2 = 12.8 MB
#define WS_HA     (WS_HLEAF + 12800000u)     // even levels out, max d=4: 4 MB
#define WS_HB     (WS_HA + 4194304u)         // odd levels out, max d=5: 16 MB

__device__ __forceinline__ float sigm(float x)   { return 1.0f / (1.0f + __expf(-x)); }
__device__ __forceinline__ float tanhf_(float x) { return 1.0f - 2.0f / (1.0f + __expf(2.0f * x)); }

__device__ __forceinline__ unsigned short f2b(float f) {
  unsigned u = __float_as_uint(f);
  u += 0x7fffu + ((u >> 16) & 1u);     // RNE (no NaN here)
  return (unsigned short)(u >> 16);
}
__device__ __forceinline__ float b2f(unsigned short s) {
  return __uint_as_float(((unsigned)s) << 16);
}

__device__ __forceinline__ unsigned fenc(float f) {
  unsigned u = __float_as_uint(f);
  return (u & 0x80000000u) ? ~u : (u | 0x80000000u);
}
__device__ __forceinline__ float fdec(unsigned e) {
  unsigned u = (e & 0x80000000u) ? (e & 0x7fffffffu) : ~e;
  return __uint_as_float(u);
}

__device__ __forceinline__ f32x4 mfma16(bf16x8 a, bf16x8 b, f32x4 c) {
  return __builtin_amdgcn_mfma_f32_16x16x32_bf16(a, b, c, 0, 0, 0);
}

__global__ __launch_bounds__(256) void decode_out(const unsigned* __restrict__ acc,
                                                  float* __restrict__ out) {
  int i = blockIdx.x * 256 + threadIdx.x;              // grid 32
  unsigned m = 0u;
  for (int s = 0; s < 32; ++s) m = max(m, acc[s * 8192 + i]);
  out[i] = fdec(m);
}

// prep: weights->bf16, sent_w transpose, acc init (emb handled by prep_hleaf)
__global__ __launch_bounds__(256) void prep_all(const float* __restrict__ wih,
                                                const float* __restrict__ whh,
                                                const float* __restrict__ sw,
                                                unsigned short* __restrict__ wihb,
                                                unsigned short* __restrict__ whhb,
                                                unsigned short* __restrict__ swtb,
                                                unsigned* __restrict__ acc) {
  int idx = blockIdx.x * 256 + threadIdx.x;            // grid 1472 = 376832
  if (idx < 49152)       wihb[idx] = f2b(wih[idx]);
  else if (idx < 98304)  whhb[idx - 49152] = f2b(whh[idx - 49152]);
  else if (idx < 114688) {
    int j = idx - 98304; int k = j >> 7, h = j & 127;
    swtb[j] = f2b(sw[h * 128 + k]);
  } else {
    acc[idx - 114688] = 0u;                            // 262144 acc words
  }
}

// ---------------------------------------------------------------------------
// prep_hleaf: reads fp32 emb ONCE -> bf16 (to LDS for the GEMM and to embb
// for later levels); H_leaf[v][:] = leaf GRU output for token v (bitwise-
// identical to the old leaf path). grid 782 x 512. Full-line stores.
// ---------------------------------------------------------------------------
__global__ __launch_bounds__(512, 2) void prep_hleaf(
    const float*          __restrict__ emb,
    unsigned short*       __restrict__ embb,
    const unsigned short* __restrict__ wih,
    const float*          __restrict__ b_ih,
    const float*          __restrict__ b_hh,
    unsigned short*       __restrict__ H)
{
  __shared__ unsigned short lds[64 * 128];
  __shared__ unsigned short hvb[64 * 128];
  const int t = threadIdx.x;
  const int base = blockIdx.x * 64;

  // stage 64 rows: fp32 load -> bf16 -> LDS (swizzled) + embb (linear)
#pragma unroll
  for (int i = 0; i < 2; ++i) {
    int g = t + 512 * i;
    int m = g >> 4, c = g & 15;
    int v = base + m; bool ok = (v < 50000); if (!ok) v = 49999;
    const float* src = emb + (size_t)v * 128 + c * 8;
    float4 f0 = *(const float4*)(src);
    float4 f1 = *(const float4*)(src + 4);
    ushort4 o0, o1;
    o0.x = f2b(f0.x); o0.y = f2b(f0.y); o0.z = f2b(f0.z); o0.w = f2b(f0.w);
    o1.x = f2b(f1.x); o1.y = f2b(f1.y); o1.z = f2b(f1.z); o1.w = f2b(f1.w);
    unsigned short* ldst = lds + m * 128 + ((c ^ (m & 15)) << 3);
    *(ushort4*)ldst       = o0;
    *(ushort4*)(ldst + 4) = o1;
    if (ok) {
      unsigned short* gdst = embb + (size_t)v * 128 + c * 8;
      *(ushort4*)gdst       = o0;
      *(ushort4*)(gdst + 4) = o1;
    }
  }

  const int w = __builtin_amdgcn_readfirstlane(t >> 6);
  const int lane = t & 63, l = lane & 15, q = lane >> 4;
  const int j = w * 16 + l;

  bf16x8 Br[4], Bz[4], Bn[4];
#pragma unroll
  for (int ks = 0; ks < 4; ++ks) {
    const int ko = ks * 32 + q * 8;
    Br[ks] = *(const bf16x8*)(wih + (size_t)j * 128 + ko);
    Bz[ks] = *(const bf16x8*)(wih + (size_t)(128 + j) * 128 + ko);
    Bn[ks] = *(const bf16x8*)(wih + (size_t)(256 + j) * 128 + ko);
  }
  const float bR = b_ih[j] + b_hh[j];
  const float bZ = b_ih[128 + j] + b_hh[128 + j];
  const float bN = b_ih[256 + j];
  const float bH = b_hh[256 + j];

  f32x4 Cr[4] = {{0,0,0,0},{0,0,0,0},{0,0,0,0},{0,0,0,0}};
  f32x4 Cz[4] = {{0,0,0,0},{0,0,0,0},{0,0,0,0},{0,0,0,0}};
  f32x4 Cn[4] = {{0,0,0,0},{0,0,0,0},{0,0,0,0},{0,0,0,0}};
  __syncthreads();

#pragma unroll
  for (int ks = 0; ks < 4; ++ks) {
    bf16x8 A[4];
#pragma unroll
    for (int mt = 0; mt < 4; ++mt) {
      int m = mt * 16 + l, c = ks * 4 + q;
      A[mt] = *(const bf16x8*)(lds + m * 128 + (((c ^ l) & 15) << 3));
    }
#pragma unroll
    for (int mt = 0; mt < 4; ++mt) {
      Cr[mt] = mfma16(A[mt], Br[ks], Cr[mt]);
      Cz[mt] = mfma16(A[mt], Bz[ks], Cz[mt]);
      Cn[mt] = mfma16(A[mt], Bn[ks], Cn[mt]);
    }
  }

#pragma unroll
  for (int mt = 0; mt < 4; ++mt)
#pragma unroll
    for (int e = 0; e < 4; ++e) {
      int b = mt * 16 + q * 4 + e;              // C/D: col=lane&15, row=quad*4+reg
      float r  = sigm(Cr[mt][e] + bR);
      float z  = sigm(Cz[mt][e] + bZ);
      float nv = tanhf_(Cn[mt][e] + bN + r * bH);
      float hv = (1.0f - z) * nv;
      hvb[b * 128 + (j ^ (q << 4))] = f2b(hv);
    }
  __syncthreads();

#pragma unroll
  for (int i = 0; i < 2; ++i) {
    int g = t + 512 * i;
    int b = g >> 4, c8 = (g & 15) * 8;
    int qq = (b >> 2) & 3;
    if (base + b < 50000) {
      uint4 v = *(const uint4*)(hvb + b * 128 + (c8 ^ (qq << 4)));
      *(uint4*)(H + (size_t)(base + b) * 128 + c8) = v;
    }
  }
}

// ---------------------------------------------------------------------------
// FUSED attn+gru, half-node blocks: grid 2n, block 512 (8 waves).
// Block (p, half) handles batch rows half*32..+32 of parent p.
// 4 barriers: (1) chs staged, (2) spart accumulated, (3) atile ready,
// (4) hvb ready. Softmax: atomicAdd partials + per-thread recompute.
// CHILD-MAX (level d+1's h) computed from chs for ALL levels; own-h max
// only at the ROOT block. Atomics only at true kernel end.
// ---------------------------------------------------------------------------
template <bool LEAF, bool ROOT>
__global__ __launch_bounds__(512, 4) void attn_gru(
    const unsigned short* __restrict__ hch,   // child h (non-leaf), rows p*256..
    const int*            __restrict__ tokc,  // LEAF: children tokens
    const unsigned short* __restrict__ hleaf, // LEAF: per-vocab leaf h
    const unsigned short* __restrict__ swt,   // 128x128 bf16 [k_u][h]
    const float*          __restrict__ sb,
    const float*          __restrict__ ctx,
    const int*            __restrict__ tok,   // THIS level's tokens
    const unsigned short* __restrict__ embb,
    const unsigned short* __restrict__ wih,
    const unsigned short* __restrict__ whh,
    const float*          __restrict__ b_ih,
    const float*          __restrict__ b_hh,
    unsigned short*       __restrict__ hout,
    unsigned*             __restrict__ acc)
{
  __shared__ unsigned short chs[128 * 128];   // 32 KB child tile
  __shared__ unsigned short atile[32 * 256];  // 16 KB gru A tile (x || h0)
  __shared__ unsigned short hvb[32 * 128];    // 8 KB hv staging
  __shared__ float spart[128];                // s partial sums (atomicAdd)

  const int p2 = blockIdx.x;
  const int p = p2 >> 1, half = p2 & 1;
  const int t = threadIdx.x;
  const int sm = t >> 4, sc = t & 15;

  // init spart before barrier 1 (accumulated after it)
  if (t < 128) spart[t] = 0.0f;

  // x gather for this half-node -> straight into atile x-region (disjoint
  // from chs; read only after barrier 3, so no hazard). Frees regs early.
  {
    const int* tp = tok + p * 64 + half * 32;
    uint4 px = *(const uint4*)(embb + (size_t)tp[sm] * 128 + sc * 8);
    *(uint4*)(atile + sm * 256 + ((sc ^ (sm & 15)) << 3)) = px;
  }

  // stage 128 child rows (4 children x 32 batch rows), XOR-swizzled
  if constexpr (LEAF) {
    const int* tokp = tokc + p * 256;
#pragma unroll
    for (int i = 0; i < 4; ++i) {
      int g = t + 512 * i, m = g >> 4, c = g & 15;
      int bg = (m >> 5) * 64 + half * 32 + (m & 31);
      uint4 v = *(const uint4*)(hleaf + (size_t)tokp[bg] * 128 + c * 8);
      *(uint4*)(chs + m * 128 + ((c ^ (m & 15)) << 3)) = v;
    }
  } else {
#pragma unroll
    for (int i = 0; i < 4; ++i) {
      int g = t + 512 * i, m = g >> 4, c = g & 15;
      int bg = (m >> 5) * 64 + half * 32 + (m & 31);
      uint4 v = *(const uint4*)(hch + ((size_t)p * 256 + bg) * 128 + c * 8);
      *(uint4*)(chs + m * 128 + ((c ^ (m & 15)) << 3)) = v;
    }
  }

  const int w = __builtin_amdgcn_readfirstlane(t >> 6);
  const int wm = w >> 2, wn = w & 3;          // wm: row-half (64), wn: col-32
  const int lane = t & 63, l = lane & 15, q = lane >> 4;
  const int j = w * 16 + l;

  bf16x8 Bs[2][4];
#pragma unroll
  for (int nt = 0; nt < 2; ++nt)
#pragma unroll
    for (int ks = 0; ks < 4; ++ks)
      Bs[nt][ks] = *(const bf16x8*)(swt + (size_t)(wn * 32 + nt * 16 + l) * 128 + ks * 32 + q * 8);

  f32x4 Cu[4][2] = {};
  __syncthreads();                                      // (1) chs staged

  // attn MFMA: wave covers rows wm*64..+64, cols wn*32..+32
#pragma unroll
  for (int ks = 0; ks < 4; ++ks) {
#pragma unroll
    for (int mt = 0; mt < 4; ++mt) {
      int m = wm * 64 + mt * 16 + l;
      int c = ks * 4 + q;
      bf16x8 A = *(const bf16x8*)(chs + m * 128 + (((c ^ (m & 15)) & 15) << 3));
      Cu[mt][0] = mfma16(A, Bs[0][ks], Cu[mt][0]);
      Cu[mt][1] = mfma16(A, Bs[1][ks], Cu[mt][1]);
    }
  }

  const float sb0 = sb[wn * 32 + l],  sb1 = sb[wn * 32 + 16 + l];
  const float cx0 = ctx[wn * 32 + l], cx1 = ctx[wn * 32 + 16 + l];
#pragma unroll
  for (int mt = 0; mt < 4; ++mt) {
    float pe[4];
#pragma unroll
    for (int e = 0; e < 4; ++e)
      pe[e] = tanhf_(Cu[mt][0][e] + sb0) * cx0 + tanhf_(Cu[mt][1][e] + sb1) * cx1;
#pragma unroll
    for (int mask = 1; mask < 16; mask <<= 1)
#pragma unroll
      for (int e = 0; e < 4; ++e)
        pe[e] += __shfl_xor(pe[e], mask, 16);
    if (l == 0) {
      int r = wm * 64 + mt * 16 + q * 4;
#pragma unroll
      for (int e = 0; e < 4; ++e) atomicAdd(&spart[r + e], pe[e]);
    }
  }
  __syncthreads();                                      // (2) spart accumulated

  // per-thread softmax (redundant across the 16 threads sharing rb; no serial
  // section). rb = t>>4 is this thread's batch row.
  float al[4];
  {
    int rb = t >> 4;
    float sv[4];
#pragma unroll
    for (int a = 0; a < 4; ++a) sv[a] = tanhf_(spart[a * 32 + rb]);
    float m = fmaxf(fmaxf(sv[0], sv[1]), fmaxf(sv[2], sv[3]));
    float e0 = __expf(sv[0] - m), e1 = __expf(sv[1] - m);
    float e2 = __expf(sv[2] - m), e3 = __expf(sv[3] - m);
    float inv = 1.0f / (e0 + e1 + e2 + e3);
    al[0] = e0 * inv; al[1] = e1 * inv; al[2] = e2 * inv; al[3] = e3 * inv;
  }

  // alpha-weighted sum -> registers (thread t: row rb=t>>4, chunk c=t&15)
  float o[8] = {0, 0, 0, 0, 0, 0, 0, 0};
  {
    int rb = t >> 4, c = t & 15;
#pragma unroll
    for (int a = 0; a < 4; ++a) {
      int m = a * 32 + rb;
      const unsigned short* rp = chs + m * 128 + ((c ^ (m & 15)) << 3);
#pragma unroll
      for (int k = 0; k < 8; ++k) o[k] += al[a] * b2f(rp[k]);
    }
  }

  // CHILD-MAX (level d+1's h) from chs — ALL levels.
  // Lane-contiguous acc mapping: word = half*4096 + t + 512e == (bg*128+j).
  float mxv[8];
  {
    const int jj = t & 127, cc = jj >> 3;
#pragma unroll
    for (int e = 0; e < 8; ++e) mxv[e] = -1e30f;
#pragma unroll
    for (int a = 0; a < 4; ++a)
#pragma unroll
      for (int e = 0; e < 8; ++e) {
        int rb = (t >> 7) + 4 * e, m = a * 32 + rb;
        float v = b2f(chs[m * 128 + (((cc ^ (m & 15)) & 15) << 3) + (jj & 7)]);
        mxv[e] = fmaxf(mxv[e], v);
      }
  }

  // h0 -> atile h0-region (x-region already written at block start)
  {
    int rb = t >> 4, c = t & 15;
    ushort4 ha, hb;
    ha.x = f2b(o[0]); ha.y = f2b(o[1]); ha.z = f2b(o[2]); ha.w = f2b(o[3]);
    hb.x = f2b(o[4]); hb.y = f2b(o[5]); hb.z = f2b(o[6]); hb.w = f2b(o[7]);
    unsigned short* dst = atile + rb * 256 + ((16 | ((c ^ (rb & 15)) & 15)) << 3);
    *(ushort4*)dst = ha;
    *(ushort4*)(dst + 4) = hb;
  }

  const unsigned short* wI = wih + (size_t)j * 128 + q * 8;
  const unsigned short* wH = whh + (size_t)j * 128 + q * 8;
  const float bR = b_ih[j] + b_hh[j];
  const float bZ = b_ih[128 + j] + b_hh[128 + j];
  const float bN = b_ih[256 + j];
  const float bH = b_hh[256 + j];
  __syncthreads();                                      // (3) atile ready

  // gru MFMA, B triple loop-loaded with 1-deep prefetch
  f32x4 Cr[2] = {{0,0,0,0},{0,0,0,0}};
  f32x4 Cz[2] = {{0,0,0,0},{0,0,0,0}};
  f32x4 Cn[2] = {{0,0,0,0},{0,0,0,0}};
  f32x4 Ch[2] = {{0,0,0,0},{0,0,0,0}};

  bf16x8 b0 = *(const bf16x8*)(wI);
  bf16x8 b1 = *(const bf16x8*)(wI + 128 * 128);
  bf16x8 b2 = *(const bf16x8*)(wI + 256 * 128);

#pragma unroll
  for (int ks = 0; ks < 8; ++ks) {
    bf16x8 c0 = b0, c1 = b1, c2 = b2;
    if (ks + 1 < 8) {
      const unsigned short* base = (ks + 1 >= 4) ? wH : wI;
      const int ko = ((ks + 1) & 3) * 32;
      b0 = *(const bf16x8*)(base + ko);
      b1 = *(const bf16x8*)(base + 128 * 128 + ko);
      b2 = *(const bf16x8*)(base + 256 * 128 + ko);
    }
#pragma unroll
    for (int mt = 0; mt < 2; ++mt) {
      int m = mt * 16 + l;
      int c = ks * 4 + q;
      bf16x8 Amt = *(const bf16x8*)(atile + m * 256 + (((c & 16) | ((c ^ l) & 15)) << 3));
      Cr[mt] = mfma16(Amt, c0, Cr[mt]);
      Cz[mt] = mfma16(Amt, c1, Cz[mt]);
      if (ks < 4) Cn[mt] = mfma16(Amt, c2, Cn[mt]);
      else        Ch[mt] = mfma16(Amt, c2, Ch[mt]);
    }
  }

  // gates; hv -> hvb (q-swizzled); ROOT tracks own-h max in regs
  float mx[2][4];
#pragma unroll
  for (int mt = 0; mt < 2; ++mt) {
#pragma unroll
    for (int e = 0; e < 4; ++e) {
      const int b = mt * 16 + q * 4 + e;        // C/D: col=lane&15, row=quad*4+reg
      float r  = sigm(Cr[mt][e] + bR);
      float z  = sigm(Cz[mt][e] + bZ);
      float nv = tanhf_(Cn[mt][e] + bN + r * (Ch[mt][e] + bH));
      int c16 = j >> 3;
      float hp = b2f(atile[b * 256 + ((16 | ((c16 ^ (b & 15)) & 15)) << 3) + (j & 7)]);
      float hv = (1.0f - z) * nv + z * hp;
      hvb[b * 128 + (j ^ (q << 4))] = f2b(hv);
      if constexpr (ROOT) mx[mt][e] = hv;
    }
  }
  __syncthreads();                                      // (4) hvb ready

  // coalesced hout store (1 chunk/thread)
  {
    int qq = (sm >> 2) & 3;
    uint4 v = *(const uint4*)(hvb + sm * 128 + ((sc * 8) ^ (qq << 4)));
    *(uint4*)(hout + ((size_t)p * 64 + half * 32 + sm) * 128 + sc * 8) = v;
  }

  // atomics at TRUE kernel end (no barrier after)
  unsigned* accs = acc + (p2 & 31) * 8192;
#pragma unroll
  for (int e = 0; e < 8; ++e)
    atomicMax(accs + half * 4096 + t + 512 * e, fenc(mxv[e]));
  if constexpr (ROOT) {
#pragma unroll
    for (int mt = 0; mt < 2; ++mt)
#pragma unroll
      for (int e = 0; e < 4; ++e) {
        const int bg = half * 32 + mt * 16 + q * 4 + e;
        atomicMax(accs + bg * 128 + j, fenc(mx[mt][e]));
      }
  }
}

extern "C" void kernel_launch(void* const* d_in, const int* in_sizes, int n_in,
                              void* d_out, int out_size, void* d_ws, size_t ws_size,
                              hipStream_t stream) {
  const int*   tokens = (const int*)d_in[0];
  const float* emb    = (const float*)d_in[1];
  const float* sent_w = (const float*)d_in[2];
  const float* sent_b = (const float*)d_in[3];
  const float* ctx_w  = (const float*)d_in[4];
  const float* w_ih   = (const float*)d_in[5];
  const float* w_hh   = (const float*)d_in[6];
  const float* b_ih   = (const float*)d_in[7];
  const float* b_hh   = (const float*)d_in[8];

  char* ws = (char*)d_ws;
  unsigned*       acc  = (unsigned*)(ws + WS_ACC);
  unsigned short* wihb = (unsigned short*)(ws + WS_WIH);
  unsigned short* whhb = (unsigned short*)(ws + WS_WHH);
  unsigned short* swtb = (unsigned short*)(ws + WS_SWT);
  unsigned short* embb = (unsigned short*)(ws + WS_EMBB);
  unsigned short* hlf  = (unsigned short*)(ws + WS_HLEAF);
  unsigned short* hA   = (unsigned short*)(ws + WS_HA);
  unsigned short* hB   = (unsigned short*)(ws + WS_HB);

  hipLaunchKernelGGL(prep_all, dim3(1472), dim3(256), 0, stream,
                     w_ih, w_hh, sent_w, wihb, whhb, swtb, acc);
  hipLaunchKernelGGL(prep_hleaf, dim3(782), dim3(512), 0, stream,
                     emb, embb, wihb, b_ih, b_hh, hlf);

  static const int offs[7] = {0, 1, 5, 21, 85, 341, 1365};
  const int* tok6 = tokens + (size_t)1365 * 64;

  for (int d = 5; d >= 0; --d) {
    int n = 1 << (2 * d);
    unsigned short* hout  = (d & 1) ? hB : hA;
    unsigned short* child = (d & 1) ? hA : hB;   // level d+1 output (non-leaf)
    if (d == 5) {
      hipLaunchKernelGGL((attn_gru<true, false>), dim3(2 * n), dim3(512), 0, stream,
                         (const unsigned short*)nullptr, tok6, hlf,
                         swtb, sent_b, ctx_w,
                         tokens + (size_t)offs[5] * 64, embb, wihb, whhb,
                         b_ih, b_hh, hout, acc);
    } else if (d > 0) {
      hipLaunchKernelGGL((attn_gru<false, false>), dim3(2 * n), dim3(512), 0, stream,
                         child, (const int*)nullptr, (const unsigned short*)nullptr,
                         swtb, sent_b, ctx_w,
                         tokens + (size_t)offs[d] * 64, embb, wihb, whhb,
                         b_ih, b_hh, hout, acc);
    } else {
      hipLaunchKernelGGL((attn_gru<false, true>), dim3(2 * n), dim3(512), 0, stream,
                         child, (const int*)nullptr, (const unsigned short*)nullptr,
                         swtb, sent_b, ctx_w,
                         tokens + (size_t)offs[0] * 64, embb, wihb, whhb,
                         b_ih, b_hh, hout, acc);
    }
  }
  hipLaunchKernelGGL(decode_out, dim3(32), dim3(256), 0, stream, acc, (float*)d_out);
}

// Round 18
// 285.731 us; speedup vs baseline: 1.0289x; 1.0129x over previous
//
#include <hip/hip_runtime.h>
#include <cstdint>
#include <cstddef>

// ---------------------------------------------------------------------------
// BatchTreeEncoder on MFMA: A=4, D=7, B=64, E=128, H=128, N_NODES=5461
// Leaves: H_leaf[v][128] precomputed once (bf16, bitwise-identical).
// Levels 5..0: fused attn+gru, half-node blocks (32 batch rows), grid 2n.
// Max strategy: child-max from staged tile at all levels; own-h at root only.
// Register state ~88 unified (56 VGPR + 32 AGPR) = 2 blocks/CU at (512,4).
// Verified walls (do NOT re-attempt): reg budgets <=85 (3 blk/CU) spill
// (r7/10/11/14); persistence spills (r10/11); global_load_lds staging -4%
// (r16); prep merge +3.5us (r17). Twice-measured optimum: 286.0/285.9 us.
// ---------------------------------------------------------------------------

typedef short  bf16x8 __attribute__((ext_vector_type(8)));
typedef float  f32x4  __attribute__((ext_vector_type(4)));

// workspace layout (bytes), total ~50 MB
#define WS_ACC    0u                         // 32*8192*4 = 1 MB
#define WS_WIH    1048576u                   // 384*128*2 = 96 KB
#define WS_WHH    (WS_WIH + 98304u)
#define WS_SWT    (WS_WHH + 98304u)          // 128*128*2 = 32 KB
#define WS_EMBB   (WS_SWT + 32768u)          // 50000*128*2 = 12.8 MB
#define WS_HLEAF  (WS_EMBB + 12800000u)      // 50000*128*2 = 12.8 MB
#define WS_HA     (WS_HLEAF + 12800000u)     // even levels out, max d=4: 4 MB
#define WS_HB     (WS_HA + 4194304u)         // odd levels out, max d=5: 16 MB

__device__ __forceinline__ float sigm(float x)   { return 1.0f / (1.0f + __expf(-x)); }
__device__ __forceinline__ float tanhf_(float x) { return 1.0f - 2.0f / (1.0f + __expf(2.0f * x)); }

__device__ __forceinline__ unsigned short f2b(float f) {
  unsigned u = __float_as_uint(f);
  u += 0x7fffu + ((u >> 16) & 1u);     // RNE (no NaN here)
  return (unsigned short)(u >> 16);
}
__device__ __forceinline__ float b2f(unsigned short s) {
  return __uint_as_float(((unsigned)s) << 16);
}

__device__ __forceinline__ unsigned fenc(float f) {
  unsigned u = __float_as_uint(f);
  return (u & 0x80000000u) ? ~u : (u | 0x80000000u);
}
__device__ __forceinline__ float fdec(unsigned e) {
  unsigned u = (e & 0x80000000u) ? (e & 0x7fffffffu) : ~e;
  return __uint_as_float(u);
}

__device__ __forceinline__ f32x4 mfma16(bf16x8 a, bf16x8 b, f32x4 c) {
  return __builtin_amdgcn_mfma_f32_16x16x32_bf16(a, b, c, 0, 0, 0);
}

__global__ __launch_bounds__(256) void decode_out(const unsigned* __restrict__ acc,
                                                  float* __restrict__ out) {
  int i = blockIdx.x * 256 + threadIdx.x;              // grid 32
  unsigned m = 0u;
  for (int s = 0; s < 32; ++s) m = max(m, acc[s * 8192 + i]);
  out[i] = fdec(m);
}

// one-shot prep: emb->bf16, weights->bf16, sent_w transpose, acc init
__global__ __launch_bounds__(256) void prep_all(const float* __restrict__ emb,
                                                const float* __restrict__ wih,
                                                const float* __restrict__ whh,
                                                const float* __restrict__ sw,
                                                unsigned short* __restrict__ embb,
                                                unsigned short* __restrict__ wihb,
                                                unsigned short* __restrict__ whhb,
                                                unsigned short* __restrict__ swtb,
                                                unsigned* __restrict__ acc) {
  size_t idx = (size_t)blockIdx.x * 256 + threadIdx.x;   // grid 7722
  if (idx < 1600000u) {                                  // 6.4M floats as float4
    float4 v = *(const float4*)(emb + idx * 4);
    ushort4 o; o.x = f2b(v.x); o.y = f2b(v.y); o.z = f2b(v.z); o.w = f2b(v.w);
    *(ushort4*)(embb + idx * 4) = o;
  } else if (idx < 1714688u) {                           // 114688 weight elems
    int i = (int)(idx - 1600000u);
    if (i < 49152)       wihb[i] = f2b(wih[i]);
    else if (i < 98304)  whhb[i - 49152] = f2b(whh[i - 49152]);
    else { int j = i - 98304; int k = j >> 7, h = j & 127; swtb[j] = f2b(sw[h * 128 + k]); }
  } else {                                               // 262144 acc words
    acc[idx - 1714688u] = 0u;
  }
}

// ---------------------------------------------------------------------------
// prep_hleaf: H_leaf[v][:] = leaf GRU output for token v (bitwise-identical
// to the old leaf path). grid 782 x 512. LDS-routed full-line stores.
// ---------------------------------------------------------------------------
__global__ __launch_bounds__(512, 2) void prep_hleaf(
    const unsigned short* __restrict__ embb,
    const unsigned short* __restrict__ wih,
    const float*          __restrict__ b_ih,
    const float*          __restrict__ b_hh,
    unsigned short*       __restrict__ H)
{
  __shared__ unsigned short lds[64 * 128];
  __shared__ unsigned short hvb[64 * 128];
  const int t = threadIdx.x;
  const int base = blockIdx.x * 64;

#pragma unroll
  for (int i = 0; i < 2; ++i) {
    int g = t + 512 * i;
    int m = g >> 4, c = g & 15;
    int v = base + m; if (v > 49999) v = 49999;
    uint4 vv = *(const uint4*)(embb + (size_t)v * 128 + c * 8);
    *(uint4*)(lds + m * 128 + ((c ^ (m & 15)) << 3)) = vv;
  }

  const int w = __builtin_amdgcn_readfirstlane(t >> 6);
  const int lane = t & 63, l = lane & 15, q = lane >> 4;
  const int j = w * 16 + l;

  bf16x8 Br[4], Bz[4], Bn[4];
#pragma unroll
  for (int ks = 0; ks < 4; ++ks) {
    const int ko = ks * 32 + q * 8;
    Br[ks] = *(const bf16x8*)(wih + (size_t)j * 128 + ko);
    Bz[ks] = *(const bf16x8*)(wih + (size_t)(128 + j) * 128 + ko);
    Bn[ks] = *(const bf16x8*)(wih + (size_t)(256 + j) * 128 + ko);
  }
  const float bR = b_ih[j] + b_hh[j];
  const float bZ = b_ih[128 + j] + b_hh[128 + j];
  const float bN = b_ih[256 + j];
  const float bH = b_hh[256 + j];

  f32x4 Cr[4] = {{0,0,0,0},{0,0,0,0},{0,0,0,0},{0,0,0,0}};
  f32x4 Cz[4] = {{0,0,0,0},{0,0,0,0},{0,0,0,0},{0,0,0,0}};
  f32x4 Cn[4] = {{0,0,0,0},{0,0,0,0},{0,0,0,0},{0,0,0,0}};
  __syncthreads();

#pragma unroll
  for (int ks = 0; ks < 4; ++ks) {
    bf16x8 A[4];
#pragma unroll
    for (int mt = 0; mt < 4; ++mt) {
      int m = mt * 16 + l, c = ks * 4 + q;
      A[mt] = *(const bf16x8*)(lds + m * 128 + (((c ^ l) & 15) << 3));
    }
#pragma unroll
    for (int mt = 0; mt < 4; ++mt) {
      Cr[mt] = mfma16(A[mt], Br[ks], Cr[mt]);
      Cz[mt] = mfma16(A[mt], Bz[ks], Cz[mt]);
      Cn[mt] = mfma16(A[mt], Bn[ks], Cn[mt]);
    }
  }

#pragma unroll
  for (int mt = 0; mt < 4; ++mt)
#pragma unroll
    for (int e = 0; e < 4; ++e) {
      int b = mt * 16 + q * 4 + e;              // C/D: col=lane&15, row=quad*4+reg
      float r  = sigm(Cr[mt][e] + bR);
      float z  = sigm(Cz[mt][e] + bZ);
      float nv = tanhf_(Cn[mt][e] + bN + r * bH);
      float hv = (1.0f - z) * nv;
      hvb[b * 128 + (j ^ (q << 4))] = f2b(hv);
    }
  __syncthreads();

#pragma unroll
  for (int i = 0; i < 2; ++i) {
    int g = t + 512 * i;
    int b = g >> 4, c8 = (g & 15) * 8;
    int qq = (b >> 2) & 3;
    if (base + b < 50000) {
      uint4 v = *(const uint4*)(hvb + b * 128 + (c8 ^ (qq << 4)));
      *(uint4*)(H + (size_t)(base + b) * 128 + c8) = v;
    }
  }
}

// ---------------------------------------------------------------------------
// FUSED attn+gru, half-node blocks: grid 2n, block 512 (8 waves).
// Block (p, half) handles batch rows half*32..+32 of parent p.
// 4 barriers: (1) chs staged, (2) spart accumulated, (3) atile ready,
// (4) hvb ready. Softmax: atomicAdd partials + per-thread recompute.
// CHILD-MAX (level d+1's h) computed from chs for ALL levels; own-h max
// only at the ROOT block. Atomics only at true kernel end.
// ---------------------------------------------------------------------------
template <bool LEAF, bool ROOT>
__global__ __launch_bounds__(512, 4) void attn_gru(
    const unsigned short* __restrict__ hch,   // child h (non-leaf), rows p*256..
    const int*            __restrict__ tokc,  // LEAF: children tokens
    const unsigned short* __restrict__ hleaf, // LEAF: per-vocab leaf h
    const unsigned short* __restrict__ swt,   // 128x128 bf16 [k_u][h]
    const float*          __restrict__ sb,
    const float*          __restrict__ ctx,
    const int*            __restrict__ tok,   // THIS level's tokens
    const unsigned short* __restrict__ embb,
    const unsigned short* __restrict__ wih,
    const unsigned short* __restrict__ whh,
    const float*          __restrict__ b_ih,
    const float*          __restrict__ b_hh,
    unsigned short*       __restrict__ hout,
    unsigned*             __restrict__ acc)
{
  __shared__ unsigned short chs[128 * 128];   // 32 KB child tile
  __shared__ unsigned short atile[32 * 256];  // 16 KB gru A tile (x || h0)
  __shared__ unsigned short hvb[32 * 128];    // 8 KB hv staging
  __shared__ float spart[128];                // s partial sums (atomicAdd)

  const int p2 = blockIdx.x;
  const int p = p2 >> 1, half = p2 & 1;
  const int t = threadIdx.x;
  const int sm = t >> 4, sc = t & 15;

  // init spart before barrier 1 (accumulated after it)
  if (t < 128) spart[t] = 0.0f;

  // x gather for this half-node -> straight into atile x-region (disjoint
  // from chs; read only after barrier 3, so no hazard). Frees regs early.
  {
    const int* tp = tok + p * 64 + half * 32;
    uint4 px = *(const uint4*)(embb + (size_t)tp[sm] * 128 + sc * 8);
    *(uint4*)(atile + sm * 256 + ((sc ^ (sm & 15)) << 3)) = px;
  }

  // stage 128 child rows (4 children x 32 batch rows), XOR-swizzled
  if constexpr (LEAF) {
    const int* tokp = tokc + p * 256;
#pragma unroll
    for (int i = 0; i < 4; ++i) {
      int g = t + 512 * i, m = g >> 4, c = g & 15;
      int bg = (m >> 5) * 64 + half * 32 + (m & 31);
      uint4 v = *(const uint4*)(hleaf + (size_t)tokp[bg] * 128 + c * 8);
      *(uint4*)(chs + m * 128 + ((c ^ (m & 15)) << 3)) = v;
    }
  } else {
#pragma unroll
    for (int i = 0; i < 4; ++i) {
      int g = t + 512 * i, m = g >> 4, c = g & 15;
      int bg = (m >> 5) * 64 + half * 32 + (m & 31);
      uint4 v = *(const uint4*)(hch + ((size_t)p * 256 + bg) * 128 + c * 8);
      *(uint4*)(chs + m * 128 + ((c ^ (m & 15)) << 3)) = v;
    }
  }

  const int w = __builtin_amdgcn_readfirstlane(t >> 6);
  const int wm = w >> 2, wn = w & 3;          // wm: row-half (64), wn: col-32
  const int lane = t & 63, l = lane & 15, q = lane >> 4;
  const int j = w * 16 + l;

  bf16x8 Bs[2][4];
#pragma unroll
  for (int nt = 0; nt < 2; ++nt)
#pragma unroll
    for (int ks = 0; ks < 4; ++ks)
      Bs[nt][ks] = *(const bf16x8*)(swt + (size_t)(wn * 32 + nt * 16 + l) * 128 + ks * 32 + q * 8);

  f32x4 Cu[4][2] = {};
  __syncthreads();                                      // (1) chs staged

  // attn MFMA: wave covers rows wm*64..+64, cols wn*32..+32
#pragma unroll
  for (int ks = 0; ks < 4; ++ks) {
#pragma unroll
    for (int mt = 0; mt < 4; ++mt) {
      int m = wm * 64 + mt * 16 + l;
      int c = ks * 4 + q;
      bf16x8 A = *(const bf16x8*)(chs + m * 128 + (((c ^ (m & 15)) & 15) << 3));
      Cu[mt][0] = mfma16(A, Bs[0][ks], Cu[mt][0]);
      Cu[mt][1] = mfma16(A, Bs[1][ks], Cu[mt][1]);
    }
  }

  const float sb0 = sb[wn * 32 + l],  sb1 = sb[wn * 32 + 16 + l];
  const float cx0 = ctx[wn * 32 + l], cx1 = ctx[wn * 32 + 16 + l];
#pragma unroll
  for (int mt = 0; mt < 4; ++mt) {
    float pe[4];
#pragma unroll
    for (int e = 0; e < 4; ++e)
      pe[e] = tanhf_(Cu[mt][0][e] + sb0) * cx0 + tanhf_(Cu[mt][1][e] + sb1) * cx1;
#pragma unroll
    for (int mask = 1; mask < 16; mask <<= 1)
#pragma unroll
      for (int e = 0; e < 4; ++e)
        pe[e] += __shfl_xor(pe[e], mask, 16);
    if (l == 0) {
      int r = wm * 64 + mt * 16 + q * 4;
#pragma unroll
      for (int e = 0; e < 4; ++e) atomicAdd(&spart[r + e], pe[e]);
    }
  }
  __syncthreads();                                      // (2) spart accumulated

  // per-thread softmax (redundant across the 16 threads sharing rb; no serial
  // section). rb = t>>4 is this thread's batch row.
  float al[4];
  {
    int rb = t >> 4;
    float sv[4];
#pragma unroll
    for (int a = 0; a < 4; ++a) sv[a] = tanhf_(spart[a * 32 + rb]);
    float m = fmaxf(fmaxf(sv[0], sv[1]), fmaxf(sv[2], sv[3]));
    float e0 = __expf(sv[0] - m), e1 = __expf(sv[1] - m);
    float e2 = __expf(sv[2] - m), e3 = __expf(sv[3] - m);
    float inv = 1.0f / (e0 + e1 + e2 + e3);
    al[0] = e0 * inv; al[1] = e1 * inv; al[2] = e2 * inv; al[3] = e3 * inv;
  }

  // alpha-weighted sum -> registers (thread t: row rb=t>>4, chunk c=t&15)
  float o[8] = {0, 0, 0, 0, 0, 0, 0, 0};
  {
    int rb = t >> 4, c = t & 15;
#pragma unroll
    for (int a = 0; a < 4; ++a) {
      int m = a * 32 + rb;
      const unsigned short* rp = chs + m * 128 + ((c ^ (m & 15)) << 3);
#pragma unroll
      for (int k = 0; k < 8; ++k) o[k] += al[a] * b2f(rp[k]);
    }
  }

  // CHILD-MAX (level d+1's h) from chs — ALL levels.
  // Lane-contiguous acc mapping: word = half*4096 + t + 512e == (bg*128+j).
  float mxv[8];
  {
    const int jj = t & 127, cc = jj >> 3;
#pragma unroll
    for (int e = 0; e < 8; ++e) mxv[e] = -1e30f;
#pragma unroll
    for (int a = 0; a < 4; ++a)
#pragma unroll
      for (int e = 0; e < 8; ++e) {
        int rb = (t >> 7) + 4 * e, m = a * 32 + rb;
        float v = b2f(chs[m * 128 + (((cc ^ (m & 15)) & 15) << 3) + (jj & 7)]);
        mxv[e] = fmaxf(mxv[e], v);
      }
  }

  // h0 -> atile h0-region (x-region already written at block start)
  {
    int rb = t >> 4, c = t & 15;
    ushort4 ha, hb;
    ha.x = f2b(o[0]); ha.y = f2b(o[1]); ha.z = f2b(o[2]); ha.w = f2b(o[3]);
    hb.x = f2b(o[4]); hb.y = f2b(o[5]); hb.z = f2b(o[6]); hb.w = f2b(o[7]);
    unsigned short* dst = atile + rb * 256 + ((16 | ((c ^ (rb & 15)) & 15)) << 3);
    *(ushort4*)dst = ha;
    *(ushort4*)(dst + 4) = hb;
  }

  const unsigned short* wI = wih + (size_t)j * 128 + q * 8;
  const unsigned short* wH = whh + (size_t)j * 128 + q * 8;
  const float bR = b_ih[j] + b_hh[j];
  const float bZ = b_ih[128 + j] + b_hh[128 + j];
  const float bN = b_ih[256 + j];
  const float bH = b_hh[256 + j];
  __syncthreads();                                      // (3) atile ready

  // gru MFMA, B triple loop-loaded with 1-deep prefetch
  f32x4 Cr[2] = {{0,0,0,0},{0,0,0,0}};
  f32x4 Cz[2] = {{0,0,0,0},{0,0,0,0}};
  f32x4 Cn[2] = {{0,0,0,0},{0,0,0,0}};
  f32x4 Ch[2] = {{0,0,0,0},{0,0,0,0}};

  bf16x8 b0 = *(const bf16x8*)(wI);
  bf16x8 b1 = *(const bf16x8*)(wI + 128 * 128);
  bf16x8 b2 = *(const bf16x8*)(wI + 256 * 128);

#pragma unroll
  for (int ks = 0; ks < 8; ++ks) {
    bf16x8 c0 = b0, c1 = b1, c2 = b2;
    if (ks + 1 < 8) {
      const unsigned short* base = (ks + 1 >= 4) ? wH : wI;
      const int ko = ((ks + 1) & 3) * 32;
      b0 = *(const bf16x8*)(base + ko);
      b1 = *(const bf16x8*)(base + 128 * 128 + ko);
      b2 = *(const bf16x8*)(base + 256 * 128 + ko);
    }
#pragma unroll
    for (int mt = 0; mt < 2; ++mt) {
      int m = mt * 16 + l;
      int c = ks * 4 + q;
      bf16x8 Amt = *(const bf16x8*)(atile + m * 256 + (((c & 16) | ((c ^ l) & 15)) << 3));
      Cr[mt] = mfma16(Amt, c0, Cr[mt]);
      Cz[mt] = mfma16(Amt, c1, Cz[mt]);
      if (ks < 4) Cn[mt] = mfma16(Amt, c2, Cn[mt]);
      else        Ch[mt] = mfma16(Amt, c2, Ch[mt]);
    }
  }

  // gates; hv -> hvb (q-swizzled); ROOT tracks own-h max in regs
  float mx[2][4];
#pragma unroll
  for (int mt = 0; mt < 2; ++mt) {
#pragma unroll
    for (int e = 0; e < 4; ++e) {
      const int b = mt * 16 + q * 4 + e;        // C/D: col=lane&15, row=quad*4+reg
      float r  = sigm(Cr[mt][e] + bR);
      float z  = sigm(Cz[mt][e] + bZ);
      float nv = tanhf_(Cn[mt][e] + bN + r * (Ch[mt][e] + bH));
      int c16 = j >> 3;
      float hp = b2f(atile[b * 256 + ((16 | ((c16 ^ (b & 15)) & 15)) << 3) + (j & 7)]);
      float hv = (1.0f - z) * nv + z * hp;
      hvb[b * 128 + (j ^ (q << 4))] = f2b(hv);
      if constexpr (ROOT) mx[mt][e] = hv;
    }
  }
  __syncthreads();                                      // (4) hvb ready

  // coalesced hout store (1 chunk/thread)
  {
    int qq = (sm >> 2) & 3;
    uint4 v = *(const uint4*)(hvb + sm * 128 + ((sc * 8) ^ (qq << 4)));
    *(uint4*)(hout + ((size_t)p * 64 + half * 32 + sm) * 128 + sc * 8) = v;
  }

  // atomics at TRUE kernel end (no barrier after)
  unsigned* accs = acc + (p2 & 31) * 8192;
#pragma unroll
  for (int e = 0; e < 8; ++e)
    atomicMax(accs + half * 4096 + t + 512 * e, fenc(mxv[e]));
  if constexpr (ROOT) {
#pragma unroll
    for (int mt = 0; mt < 2; ++mt)
#pragma unroll
      for (int e = 0; e < 4; ++e) {
        const int bg = half * 32 + mt * 16 + q * 4 + e;
        atomicMax(accs + bg * 128 + j, fenc(mx[mt][e]));
      }
  }
}

extern "C" void kernel_launch(void* const* d_in, const int* in_sizes, int n_in,
                              void* d_out, int out_size, void* d_ws, size_t ws_size,
                              hipStream_t stream) {
  const int*   tokens = (const int*)d_in[0];
  const float* emb    = (const float*)d_in[1];
  const float* sent_w = (const float*)d_in[2];
  const float* sent_b = (const float*)d_in[3];
  const float* ctx_w  = (const float*)d_in[4];
  const float* w_ih   = (const float*)d_in[5];
  const float* w_hh   = (const float*)d_in[6];
  const float* b_ih   = (const float*)d_in[7];
  const float* b_hh   = (const float*)d_in[8];

  char* ws = (char*)d_ws;
  unsigned*       acc  = (unsigned*)(ws + WS_ACC);
  unsigned short* wihb = (unsigned short*)(ws + WS_WIH);
  unsigned short* whhb = (unsigned short*)(ws + WS_WHH);
  unsigned short* swtb = (unsigned short*)(ws + WS_SWT);
  unsigned short* embb = (unsigned short*)(ws + WS_EMBB);
  unsigned short* hlf  = (unsigned short*)(ws + WS_HLEAF);
  unsigned short* hA   = (unsigned short*)(ws + WS_HA);
  unsigned short* hB   = (unsigned short*)(ws + WS_HB);

  hipLaunchKernelGGL(prep_all, dim3(7722), dim3(256), 0, stream,
                     emb, w_ih, w_hh, sent_w, embb, wihb, whhb, swtb, acc);
  hipLaunchKernelGGL(prep_hleaf, dim3(782), dim3(512), 0, stream,
                     embb, wihb, b_ih, b_hh, hlf);

  static const int offs[7] = {0, 1, 5, 21, 85, 341, 1365};
  const int* tok6 = tokens + (size_t)1365 * 64;

  for (int d = 5; d >= 0; --d) {
    int n = 1 << (2 * d);
    unsigned short* hout  = (d & 1) ? hB : hA;
    unsigned short* child = (d & 1) ? hA : hB;   // level d+1 output (non-leaf)
    if (d == 5) {
      hipLaunchKernelGGL((attn_gru<true, false>), dim3(2 * n), dim3(512), 0, stream,
                         (const unsigned short*)nullptr, tok6, hlf,
                         swtb, sent_b, ctx_w,
                         tokens + (size_t)offs[5] * 64, embb, wihb, whhb,
                         b_ih, b_hh, hout, acc);
    } else if (d > 0) {
      hipLaunchKernelGGL((attn_gru<false, false>), dim3(2 * n), dim3(512), 0, stream,
                         child, (const int*)nullptr, (const unsigned short*)nullptr,
                         swtb, sent_b, ctx_w,
                         tokens + (size_t)offs[d] * 64, embb, wihb, whhb,
                         b_ih, b_hh, hout, acc);
    } else {
      hipLaunchKernelGGL((attn_gru<false, true>), dim3(2 * n), dim3(512), 0, stream,
                         child, (const int*)nullptr, (const unsigned short*)nullptr,
                         swtb, sent_b, ctx_w,
                         tokens + (size_t)offs[0] * 64, embb, wihb, whhb,
                         b_ih, b_hh, hout, acc);
    }
  }
  hipLaunchKernelGGL(decode_out, dim3(32), dim3(256), 0, stream, acc, (float*)d_out);
}